// Round 9
// baseline (23270.544 us; speedup 1.0000x reference)
//
#include <hip/hip_runtime.h>

#define HID 64
#define NF 8

typedef float f2 __attribute__((ext_vector_type(2)));
typedef float f4 __attribute__((ext_vector_type(4)));

template <int CTRL>
__device__ __forceinline__ float qp(float x) {
  return __int_as_float(
      __builtin_amdgcn_update_dpp(0, __float_as_int(x), CTRL, 0xF, 0xF, true));
}
__device__ __forceinline__ float sigm(float x) {
  float e = __expf(-x);
  return __fdividef(1.0f, 1.0f + e);
}
__device__ __forceinline__ float tanhe(float x) {
  float e = __expf(-2.0f * x);
  return __fdividef(2.0f, 1.0f + e) - 1.0f;
}
__device__ __forceinline__ int ldc(int* p) {
  return __hip_atomic_load(p, __ATOMIC_ACQUIRE, __HIP_MEMORY_SCOPE_WORKGROUP);
}
__device__ __forceinline__ void stc(int* p, int v) {
  __hip_atomic_store(p, v, __ATOMIC_RELEASE, __HIP_MEMORY_SCOPE_WORKGROUP);
}

// 256 threads = 4 waves, 1/SIMD (512-VGPR budget):
//  w0: FULL layer-0 cell in one wave. lane=unit; quad-K-split dot (lane k of
//      each quad reads K-chunk [16k,16k+16) of h0; 4 b128 broadcast reads);
//      rotated-unit slots so 12 quad_perm DPP gather each lane's own unit's
//      4 gate sums; act fully in-lane; c,h in registers; h0 -> LDS for
//      consumers. Recurrence = same-wave LDS roundtrip, NO cross-wave sync.
//      Only poll: xS ring, once per 16 phases (16-phase slack).
//  w1: P[s] = Wih1 @ h0[s]   (feed-forward; adds lag, not rate)
//  w2: FULL layer-1 cell (h1 recurrence self-contained, reads P + h1 ring)
//  w3: xS bursts (teacher-forced x-projection computed 2 chunks ahead),
//      head (hid->out->round, lag 4), obuf flush, all off-path.
// Forward-only chain w0->w1->w2->w3; the single back-edge (xS) has ~16
// phases of slack -> steady rate = max(single-wave cell cycle).
__global__ __launch_bounds__(256, 1) void decoder_p9(
    const float* __restrict__ h0in, const float* __restrict__ c0in,
    const float* __restrict__ diffp, const float* __restrict__ target,
    const float* __restrict__ Wih0, const float* __restrict__ Whh0,
    const float* __restrict__ bih0, const float* __restrict__ bhh0,
    const float* __restrict__ Wih1, const float* __restrict__ Whh1,
    const float* __restrict__ bih1, const float* __restrict__ bhh1,
    const float* __restrict__ Whid, const float* __restrict__ bhidp,
    const float* __restrict__ Woutp, const float* __restrict__ boutp,
    float* __restrict__ outp, const int T)
{
  const int tid = threadIdx.x;
  const int wv = tid >> 6;
  const int l  = tid & 63;
  const int q  = l >> 2;
  const int k  = l & 3;

  __shared__ alignas(16) float xb[4][16][256];   // xS ring: [chunk&3][step][gate*64+unit]
  __shared__ alignas(16) float tbT[4][128];      // staged target rows per chunk
  __shared__ alignas(16) float h0L[4][64];
  __shared__ alignas(16) float h1L[32][64];
  __shared__ alignas(16) float Pld[4][256];      // [slot][gate*64+unit]
  __shared__ alignas(16) float hidb[32];
  __shared__ alignas(16) float obuf[64 * NF];
  __shared__ int cnt[4];                         // 0=L0, 1=L1a, 2=L1b, 3=io

  // ---- per-wave registers ----
  f2 wq[128];                       // w0/w1/w2: 16 slots x 8 f2
  float bg[4] = {0, 0, 0, 0};
  float cS = 0.f, hS = 0.f;
  // w3:
  f2 wt[16];  float xd[4] = {0, 0, 0, 0};
  f2 wh[16];  float bh2[2] = {0, 0};
  f2 wo[4];   float bo = 0.f;

  const int nch = T >> 4;           // T assumed multiple of 16, >= 64

  if (wv <= 2) {
    const float* W = (wv == 0) ? Whh0 : (wv == 1) ? Wih1 : Whh1;
    #pragma unroll
    for (int i = 0; i < 4; ++i)
      #pragma unroll
      for (int j = 0; j < 4; ++j) {
        const int row = 64 * j + 4 * q + ((k + i) & 3);
        const float* rp = W + row * HID + 16 * k;
        #pragma unroll
        for (int c = 0; c < 4; ++c) {
          f4 v = *(const f4*)(rp + 4 * c);
          wq[(i * 4 + j) * 8 + 2 * c]     = v.lo;
          wq[(i * 4 + j) * 8 + 2 * c + 1] = v.hi;
        }
      }
    if (wv == 0) {
      #pragma unroll
      for (int j = 0; j < 4; ++j) bg[j] = bih0[64 * j + l] + bhh0[64 * j + l];
      cS = c0in[l];
      h0L[3][l] = h0in[l];
    } else if (wv == 2) {
      #pragma unroll
      for (int j = 0; j < 4; ++j) bg[j] = bih1[64 * j + l] + bhh1[64 * j + l];
      cS = c0in[64 + l];
      h1L[31][l] = h0in[64 + l];
    }
    if (wv == 0 && l < 3) cnt[l] = 0;   // cnt[0..2]
  } else {
    // ---- w3 weights ----
    #pragma unroll
    for (int j = 0; j < 4; ++j) {
      const float* ra = Wih0 + (64 * j + l) * 14;
      #pragma unroll
      for (int c = 0; c < 4; ++c) wt[j * 4 + c] = (f2){ra[2 * c], ra[2 * c + 1]};
      float s = 0.f;
      #pragma unroll
      for (int m = 0; m < 6; ++m) s += ra[8 + m] * diffp[m];
      xd[j] = s;
    }
    #pragma unroll
    for (int i = 0; i < 2; ++i) {
      const float* rp = Whid + (2 * q + i) * HID + 16 * k;
      #pragma unroll
      for (int c = 0; c < 4; ++c) {
        f4 v = *(const f4*)(rp + 4 * c);
        wh[i * 8 + 2 * c]     = v.lo;
        wh[i * 8 + 2 * c + 1] = v.hi;
      }
      bh2[i] = bhidp[2 * q + i];
    }
    if (l < 32) {
      const float* rp = Woutp + (l >> 2) * 32 + 8 * k;
      f4 a = *(const f4*)rp, b = *(const f4*)(rp + 4);
      wo[0] = a.lo; wo[1] = a.hi; wo[2] = b.lo; wo[3] = b.hi;
      bo = boutp[l >> 2];
    }
    // ---- preloop: xS chunks 0,1 ----
    if (l < 30) *(f4*)&tbT[0][4 * l] = *(const f4*)&target[4 * l];
    if (l < 32) *(f4*)&tbT[1][4 * l] = *(const f4*)&target[120 + 4 * l];
    #pragma unroll 1
    for (int i = 0; i < 16; ++i) {   // chunk 0
      if (i == 0) {
        #pragma unroll
        for (int j = 0; j < 4; ++j) xb[0][0][j * 64 + l] = 0.f;
      } else {
        const float* tr = &tbT[0][8 * (i - 1)];
        f4 r0 = *(const f4*)tr, r1 = *(const f4*)(tr + 4);
        #pragma unroll
        for (int j = 0; j < 4; ++j) {
          f2 s = wt[j * 4 + 0] * r0.lo; s += wt[j * 4 + 1] * r0.hi;
          s += wt[j * 4 + 2] * r1.lo;  s += wt[j * 4 + 3] * r1.hi;
          xb[0][i][j * 64 + l] = xd[j] + s.x + s.y;
        }
      }
    }
    #pragma unroll 1
    for (int i = 0; i < 16; ++i) {   // chunk 1
      const float* tr = &tbT[1][8 * i];
      f4 r0 = *(const f4*)tr, r1 = *(const f4*)(tr + 4);
      #pragma unroll
      for (int j = 0; j < 4; ++j) {
        f2 s = wt[j * 4 + 0] * r0.lo; s += wt[j * 4 + 1] * r0.hi;
        s += wt[j * 4 + 2] * r1.lo;  s += wt[j * 4 + 3] * r1.hi;
        xb[1][i][j * 64 + l] = xd[j] + s.x + s.y;
      }
    }
    if (l == 0) cnt[3] = 2;
  }
  __syncthreads();

  const int tend = T + 1;

  if (wv == 0) {
    // ================= layer-0 cell =================
    for (int t = 0; t <= tend; ++t) {
      if (t < T) {
        if ((t & 15) == 0)
          while (ldc(&cnt[3]) < (t >> 4) + 1) {}
        const float* hp = &h0L[(t - 1) & 3][16 * k];
        f4 hv[4] = {*(const f4*)hp, *(const f4*)(hp + 4),
                    *(const f4*)(hp + 8), *(const f4*)(hp + 12)};
        float xg0 = xb[(t >> 4) & 3][t & 15][l];
        float xg1 = xb[(t >> 4) & 3][t & 15][64 + l];
        float xg2 = xb[(t >> 4) & 3][t & 15][128 + l];
        float xg3 = xb[(t >> 4) & 3][t & 15][192 + l];
        f2 P[16];
        #pragma unroll
        for (int z = 0; z < 16; ++z) P[z] = (f2){0.f, 0.f};
        #pragma unroll
        for (int c = 0; c < 4; ++c) {
          f4 v = hv[c];
          #pragma unroll
          for (int z = 0; z < 16; ++z) {
            P[z] += wq[z * 8 + 2 * c] * v.lo;
            P[z] += wq[z * 8 + 2 * c + 1] * v.hi;
          }
        }
        float Ps[16];
        #pragma unroll
        for (int z = 0; z < 16; ++z) Ps[z] = P[z].x + P[z].y;
        float G[4];
        #pragma unroll
        for (int j = 0; j < 4; ++j)
          G[j] = ((Ps[j] + qp<0x93>(Ps[4 + j])) +
                  (qp<0x4E>(Ps[8 + j]) + qp<0x39>(Ps[12 + j]))) + bg[j];
        G[0] += xg0; G[1] += xg1; G[2] += xg2; G[3] += xg3;
        float si = sigm(G[0]), sf = sigm(G[1]);
        float tg = tanhe(G[2]), so = sigm(G[3]);
        cS = sf * cS + si * tg;
        hS = so * tanhe(cS);
        h0L[t & 3][l] = hS;
      }
      if (l == 0) stc(&cnt[0], t + 1);
    }
  } else if (wv == 1) {
    // ================= L1 input half =================
    for (int t = 0; t <= tend; ++t) {
      if (t >= 1 && t <= T) {
        const int s = t - 1;
        while (ldc(&cnt[0]) < s + 1) {}
        const float* hp = &h0L[s & 3][16 * k];
        f4 hv[4] = {*(const f4*)hp, *(const f4*)(hp + 4),
                    *(const f4*)(hp + 8), *(const f4*)(hp + 12)};
        f2 P[16];
        #pragma unroll
        for (int z = 0; z < 16; ++z) P[z] = (f2){0.f, 0.f};
        #pragma unroll
        for (int c = 0; c < 4; ++c) {
          f4 v = hv[c];
          #pragma unroll
          for (int z = 0; z < 16; ++z) {
            P[z] += wq[z * 8 + 2 * c] * v.lo;
            P[z] += wq[z * 8 + 2 * c + 1] * v.hi;
          }
        }
        float Ps[16];
        #pragma unroll
        for (int z = 0; z < 16; ++z) Ps[z] = P[z].x + P[z].y;
        #pragma unroll
        for (int j = 0; j < 4; ++j)
          Pld[s & 3][j * 64 + l] =
              (Ps[j] + qp<0x93>(Ps[4 + j])) +
              (qp<0x4E>(Ps[8 + j]) + qp<0x39>(Ps[12 + j]));
      }
      if (l == 0) stc(&cnt[1], t + 1);
    }
  } else if (wv == 2) {
    // ================= layer-1 cell =================
    for (int t = 0; t <= tend; ++t) {
      if (t >= 2) {
        const int s = t - 2;
        while (ldc(&cnt[1]) < t) {}
        float Pg0 = Pld[s & 3][l],        Pg1 = Pld[s & 3][64 + l];
        float Pg2 = Pld[s & 3][128 + l],  Pg3 = Pld[s & 3][192 + l];
        const float* hp = &h1L[(s - 1) & 31][16 * k];
        f4 hv[4] = {*(const f4*)hp, *(const f4*)(hp + 4),
                    *(const f4*)(hp + 8), *(const f4*)(hp + 12)};
        f2 P[16];
        #pragma unroll
        for (int z = 0; z < 16; ++z) P[z] = (f2){0.f, 0.f};
        #pragma unroll
        for (int c = 0; c < 4; ++c) {
          f4 v = hv[c];
          #pragma unroll
          for (int z = 0; z < 16; ++z) {
            P[z] += wq[z * 8 + 2 * c] * v.lo;
            P[z] += wq[z * 8 + 2 * c + 1] * v.hi;
          }
        }
        float Ps[16];
        #pragma unroll
        for (int z = 0; z < 16; ++z) Ps[z] = P[z].x + P[z].y;
        float G[4];
        #pragma unroll
        for (int j = 0; j < 4; ++j)
          G[j] = ((Ps[j] + qp<0x93>(Ps[4 + j])) +
                  (qp<0x4E>(Ps[8 + j]) + qp<0x39>(Ps[12 + j]))) + bg[j];
        G[0] += Pg0; G[1] += Pg1; G[2] += Pg2; G[3] += Pg3;
        float si = sigm(G[0]), sf = sigm(G[1]);
        float tg = tanhe(G[2]), so = sigm(G[3]);
        cS = sf * cS + si * tg;
        hS = so * tanhe(cS);
        h1L[s & 31][l] = hS;
      }
      if (l == 0) stc(&cnt[2], t + 1);
    }
  } else {
    // ================= io / xproj / head =================
    for (int t = 0; t <= tend; ++t) {
      // xS burst: produce chunk (t>>4)+2
      if ((t & 15) == 0) {
        const int c2 = (t >> 4) + 2;
        if (c2 < nch) {
          if (l < 32)
            *(f4*)&tbT[c2 & 3][4 * l] =
                *(const f4*)&target[(16 * c2 - 1) * 8 + 4 * l];
          #pragma unroll 1
          for (int i = 0; i < 16; ++i) {
            const float* tr = &tbT[c2 & 3][8 * i];
            f4 r0 = *(const f4*)tr, r1 = *(const f4*)(tr + 4);
            #pragma unroll
            for (int j = 0; j < 4; ++j) {
              f2 s = wt[j * 4 + 0] * r0.lo; s += wt[j * 4 + 1] * r0.hi;
              s += wt[j * 4 + 2] * r1.lo;  s += wt[j * 4 + 3] * r1.hi;
              xb[c2 & 3][i][j * 64 + l] = xd[j] + s.x + s.y;
            }
          }
          if (l == 0) stc(&cnt[3], c2 + 1);
        }
      }
      // head(s = t-4)
      if (t >= 4 && t - 4 < T) {
        const int s = t - 4;
        while (ldc(&cnt[2]) < t - 1) {}
        const float* hp = &h1L[s & 31][16 * k];
        f4 hv[4] = {*(const f4*)hp, *(const f4*)(hp + 4),
                    *(const f4*)(hp + 8), *(const f4*)(hp + 12)};
        f2 p0 = {0.f, 0.f}, p1 = {0.f, 0.f};
        #pragma unroll
        for (int c = 0; c < 4; ++c) {
          f4 v = hv[c];
          p0 += wh[2 * c] * v.lo;     p0 += wh[2 * c + 1] * v.hi;
          p1 += wh[8 + 2 * c] * v.lo; p1 += wh[8 + 2 * c + 1] * v.hi;
        }
        float S0 = p0.x + p0.y; S0 += qp<0xB1>(S0); S0 += qp<0x4E>(S0);
        float S1 = p1.x + p1.y; S1 += qp<0xB1>(S1); S1 += qp<0x4E>(S1);
        if (k < 2) hidb[2 * q + k] = ((k == 0) ? S0 : S1) + bh2[k];
        if (l < 32) {
          const float* hb = &hidb[8 * k];
          f4 ha = *(const f4*)hb, hc = *(const f4*)(hb + 4);
          f2 po = wo[0] * ha.lo; po += wo[1] * ha.hi;
          po += wo[2] * hc.lo;  po += wo[3] * hc.hi;
          float So = po.x + po.y; So += qp<0xB1>(So); So += qp<0x4E>(So);
          if (k == 0) obuf[(s & 63) * NF + (l >> 2)] = rintf(So + bo);
        }
      }
      // flush outs
      if ((t & 31) == 4 && t >= 36) {
        const int s = (t - 36) + (l >> 1);
        const int off = (l & 1) * 4;
        *(f4*)&outp[s * NF + off] = *(const f4*)&obuf[(s & 63) * NF + off];
      }
    }
  }
  __syncthreads();

  // ================= EPILOGUE =================
  if (wv == 3) {
    // remaining heads: s = T-2, T-1
    for (int s = T - 2; s < T; ++s) {
      const float* hp = &h1L[s & 31][16 * k];
      f4 hv[4] = {*(const f4*)hp, *(const f4*)(hp + 4),
                  *(const f4*)(hp + 8), *(const f4*)(hp + 12)};
      f2 p0 = {0.f, 0.f}, p1 = {0.f, 0.f};
      #pragma unroll
      for (int c = 0; c < 4; ++c) {
        f4 v = hv[c];
        p0 += wh[2 * c] * v.lo;     p0 += wh[2 * c + 1] * v.hi;
        p1 += wh[8 + 2 * c] * v.lo; p1 += wh[8 + 2 * c + 1] * v.hi;
      }
      float S0 = p0.x + p0.y; S0 += qp<0xB1>(S0); S0 += qp<0x4E>(S0);
      float S1 = p1.x + p1.y; S1 += qp<0xB1>(S1); S1 += qp<0x4E>(S1);
      if (k < 2) hidb[2 * q + k] = ((k == 0) ? S0 : S1) + bh2[k];
      __builtin_amdgcn_s_waitcnt(0);   // lgkm drain before in-wave read
      if (l < 32) {
        const float* hb = &hidb[8 * k];
        f4 ha = *(const f4*)hb, hc = *(const f4*)(hb + 4);
        f2 po = wo[0] * ha.lo; po += wo[1] * ha.hi;
        po += wo[2] * hc.lo;  po += wo[3] * hc.hi;
        float So = po.x + po.y; So += qp<0xB1>(So); So += qp<0x4E>(So);
        if (k == 0) obuf[(s & 63) * NF + (l >> 2)] = rintf(So + bo);
      }
    }
    // tail flush
    const int tL = (T + 1) - (((T + 1) - 4) & 31);
    const int s0 = (tL >= 36) ? (tL - 4) : 0;
    for (int idx = l; idx < (T - s0) * 2; idx += 64) {
      const int s = s0 + (idx >> 1);
      const int off = (idx & 1) * 4;
      *(f4*)&outp[s * NF + off] = *(const f4*)&obuf[(s & 63) * NF + off];
    }
  }
  const int base = T * NF;
  if (wv == 0) {
    outp[base + l]       = hS;   // h_final layer 0
    outp[base + 128 + l] = cS;   // c_final layer 0
  } else if (wv == 2) {
    outp[base + 64 + l]  = hS;   // h_final layer 1
    outp[base + 192 + l] = cS;   // c_final layer 1
  }
}

extern "C" void kernel_launch(void* const* d_in, const int* in_sizes, int n_in,
                              void* d_out, int out_size, void* d_ws, size_t ws_size,
                              hipStream_t stream) {
  const float* h0in   = (const float*)d_in[1];
  const float* c0in   = (const float*)d_in[2];
  const float* diffp  = (const float*)d_in[3];
  const float* target = (const float*)d_in[4];
  const float* Wih0   = (const float*)d_in[5];
  const float* Whh0   = (const float*)d_in[6];
  const float* bih0   = (const float*)d_in[7];
  const float* bhh0   = (const float*)d_in[8];
  const float* Wih1   = (const float*)d_in[9];
  const float* Whh1   = (const float*)d_in[10];
  const float* bih1   = (const float*)d_in[11];
  const float* bhh1   = (const float*)d_in[12];
  const float* Whid   = (const float*)d_in[13];
  const float* bhidp  = (const float*)d_in[14];
  const float* Woutp  = (const float*)d_in[15];
  const float* boutp  = (const float*)d_in[16];
  float* outp = (float*)d_out;
  const int T = in_sizes[4] / NF;

  decoder_p9<<<dim3(1), dim3(256), 0, stream>>>(
      h0in, c0in, diffp, target,
      Wih0, Whh0, bih0, bhh0,
      Wih1, Whh1, bih1, bhh1,
      Whid, bhidp, Woutp, boutp,
      outp, T);
}

// Round 10
// 16526.471 us; speedup vs baseline: 1.4081x; 1.4081x over previous
//
#include <hip/hip_runtime.h>

#define HID 64
#define NF 8

typedef float f2 __attribute__((ext_vector_type(2)));
typedef float f4 __attribute__((ext_vector_type(4)));

template <int CTRL>
__device__ __forceinline__ float qp(float x) {
  return __int_as_float(
      __builtin_amdgcn_update_dpp(0, __float_as_int(x), CTRL, 0xF, 0xF, true));
}
__device__ __forceinline__ int ldc(int* p) {
  return __hip_atomic_load(p, __ATOMIC_ACQUIRE, __HIP_MEMORY_SCOPE_WORKGROUP);
}
__device__ __forceinline__ void adc(int* p) {
  __hip_atomic_fetch_add(p, 1, __ATOMIC_RELEASE, __HIP_MEMORY_SCOPE_WORKGROUP);
}

// 512 threads = 8 waves, 2/SIMD. DECOUPLED groups (no cross-group lockstep):
//  Group A (waves 0-3): layer-0 cell (R7's proven quad scheme) + x-proj +
//    tbuf prefetch. Runs ahead; h0 ring depth 8; checks B's counter only
//    once per 4 phases through a cached value (ring-space back-edge, ~6 slack).
//  Group B (waves 4-7): layer-1 cell + head (hid on wv4, out+flush on wv5).
//    Polls A's counter via cache (instant in steady state since A leads);
//    per-phase sync = own 4-wave quorum only.
// Counters: cnt[0]=A quorum, cnt[1]=B quorum (fetch_add 1 per wave per phase,
// quorum target 4t — R7-proven). No s_barrier in the loop -> no vmcnt drains.
// All cell math / DPP reduce / act / lags byte-identical to R7.
__global__ __launch_bounds__(512, 2) void decoder_p10(
    const float* __restrict__ h0in, const float* __restrict__ c0in,
    const float* __restrict__ diffp, const float* __restrict__ target,
    const float* __restrict__ Wih0, const float* __restrict__ Whh0,
    const float* __restrict__ bih0, const float* __restrict__ bhh0,
    const float* __restrict__ Wih1, const float* __restrict__ Whh1,
    const float* __restrict__ bih1, const float* __restrict__ bhh1,
    const float* __restrict__ Whid, const float* __restrict__ bhidp,
    const float* __restrict__ Woutp, const float* __restrict__ boutp,
    float* __restrict__ outp, const int T)
{
  const int tid = threadIdx.x;
  const int wv  = tid >> 6;
  const int l   = tid & 63;
  const int q   = l >> 2;
  const int k   = l & 3;
  const bool isL1 = (wv >= 4);
  const int u   = 16 * (wv & 3) + q;
  const int r   = 64 * k + u;
  const bool isk0 = (k == 0);
  const bool isg  = (k == 2);
  const float am = isg ? 2.0f : 1.0f;
  const float ab = isg ? -1.0f : 0.0f;

  __shared__ alignas(256) float h0r[8][64];
  __shared__ alignas(256) float h1r[8][64];
  __shared__ alignas(256) float hidS[4][32];
  __shared__ alignas(256) float obuf[64 * NF];
  __shared__ alignas(256) float tbuf[2][32 * NF];
  __shared__ int cnt[2];

  f2 wq[64];
  f2 wxv[4];
  f2 wh[16];
  f2 wo[4];
  float b_ = 0.f, xd = 0.f;
  float bhA = 0.f, bhB = 0.f, bo_ = 0.f;

  if (isL1) {
    // L1 weights (R7 layout): K-chunk k of [h0;h1], rotation (c+2k)&7
    const float* Wsrc = (k < 2) ? Wih1 : Whh1;
    const int co = 32 * (k & 1);
    #pragma unroll
    for (int j = 0; j < 4; ++j) {
      const int row = 64 * ((k + j) & 3) + u;
      const float* rp = Wsrc + row * HID + co;
      #pragma unroll
      for (int c = 0; c < 8; ++c) {
        f4 v = *(const f4*)(rp + 4 * ((c + 2 * k) & 7));
        wq[16 * j + 2 * c]     = v.lo;
        wq[16 * j + 2 * c + 1] = v.hi;
      }
    }
    b_ = bih1[r] + bhh1[r];
    if (wv == 4) {
      // head stage 1 (hid) weights: rows 2q, 2q+1, chunk 16k, rot (c+k)&3
      #pragma unroll
      for (int i = 0; i < 2; ++i) {
        const float* rp = Whid + (2 * q + i) * HID + 16 * k;
        #pragma unroll
        for (int c = 0; c < 4; ++c) {
          f4 v = *(const f4*)(rp + 4 * ((c + k) & 3));
          wh[8 * i + 2 * c]     = v.lo;
          wh[8 * i + 2 * c + 1] = v.hi;
        }
      }
      bhA = bhidp[2 * q];
      bhB = bhidp[2 * q + 1];
    } else if (wv == 5 && q < 8) {
      // head stage 2 (out) weights: row q, chunk 8k, rot (c+k)&1
      const float* rp = Woutp + q * 32 + 8 * k;
      #pragma unroll
      for (int c = 0; c < 2; ++c) {
        f4 v = *(const f4*)(rp + 4 * ((c + k) & 1));
        wo[2 * c]     = v.lo;
        wo[2 * c + 1] = v.hi;
      }
      bo_ = boutp[q];
    }
  } else {
    // L0 weights: K-chunk k of h0, rotation (c+k)&3
    #pragma unroll
    for (int j = 0; j < 4; ++j) {
      const int row = 64 * ((k + j) & 3) + u;
      const float* rp = Whh0 + row * HID + 16 * k;
      #pragma unroll
      for (int c = 0; c < 4; ++c) {
        f4 v = *(const f4*)(rp + 4 * ((c + k) & 3));
        wq[8 * j + 2 * c]     = v.lo;
        wq[8 * j + 2 * c + 1] = v.hi;
      }
    }
    b_ = bih0[r] + bhh0[r];
    const float* ra = Wih0 + r * 14;
    #pragma unroll
    for (int c = 0; c < 4; ++c) wxv[c] = (f2){ra[2 * c], ra[2 * c + 1]};
    xd = 0.f;
    #pragma unroll
    for (int m = 0; m < 6; ++m) xd += ra[8 + m] * diffp[m];
  }

  float cS = 0.f, hS = 0.f;
  if (isk0) cS = isL1 ? c0in[64 + u] : c0in[u];
  // seeds at slot 7 (= states at t-1 for t=0)
  if (tid < 64) h0r[7][tid] = h0in[tid];
  else if (tid < 128) h1r[7][tid - 64] = h0in[tid];
  if (wv == 2) {  // initial tbuf chunks 0,1
    *(f4*)&((float*)tbuf)[l * 8]     = *(const f4*)&target[l * 8];
    *(f4*)&((float*)tbuf)[l * 8 + 4] = *(const f4*)&target[l * 8 + 4];
  }
  if (tid < 2) cnt[tid] = 0;
  __syncthreads();

  if (!isL1) {
    // ================= GROUP A: layer-0, runs ahead =================
    int cached1 = 0;
    float xc = 0.f;   // x(0) = zeros
    for (int t = 0; t < T; ++t) {
      // ring-space back-edge, checked once per 4 phases (slack ~6)
      if ((t & 3) == 0 && t >= 8) {
        const int need = 4 * (t - 6);
        while (cached1 < need) cached1 = ldc(&cnt[1]);
      }
      while (ldc(&cnt[0]) < 4 * t) {}   // own 4-wave quorum
      // ---- layer-0 cell: h0[t] = cell(x(t), h0[t-1]) ----
      {
        const float* base = &h0r[(t - 1) & 7][16 * k];
        f2 P0 = {0.f,0.f}, P1 = {0.f,0.f}, P2 = {0.f,0.f}, P3 = {0.f,0.f};
        #pragma unroll
        for (int c = 0; c < 4; ++c) {
          f4 v = *(const f4*)(base + 4 * ((c + k) & 3));
          P0 += wq[2*c] * v.lo;      P0 += wq[2*c+1] * v.hi;
          P1 += wq[8+2*c] * v.lo;    P1 += wq[8+2*c+1] * v.hi;
          P2 += wq[16+2*c] * v.lo;   P2 += wq[16+2*c+1] * v.hi;
          P3 += wq[24+2*c] * v.lo;   P3 += wq[24+2*c+1] * v.hi;
        }
        float p0 = P0.x + P0.y, p1 = P1.x + P1.y;
        float p2 = P2.x + P2.y, p3 = P3.x + P3.y;
        float g = ((p0 + qp<0x39>(p3)) + (qp<0x4E>(p2) + qp<0x93>(p1))) + b_ + xc;
        float e = __expf(-g * am);
        float s = __fdividef(1.0f, 1.0f + e);
        float a = fmaf(s, am, ab);
        float A1 = qp<0xB1>(a), A2 = qp<0x4E>(a), A3 = qp<0x1B>(a);
        if (isk0) {
          cS = A1 * cS + a * A2;
          float e2 = __expf(-2.0f * cS);
          hS = A3 * (__fdividef(2.0f, 1.0f + e2) - 1.0f);
          h0r[t & 7][u] = hS;
        }
      }
      // ---- x-proj for phase t+1 (uses target[t]) ----
      if (t < T - 1) {
        const f4* trow = (const f4*)&tbuf[(t >> 5) & 1][(t & 31) * NF];
        f4 r0 = trow[0], r1 = trow[1];
        f2 s = wxv[0] * r0.lo; s += wxv[1] * r0.hi;
        s += wxv[2] * r1.lo;   s += wxv[3] * r1.hi;
        xc = xd + s.x + s.y;
      } else xc = 0.f;
      // ---- wv1: tbuf prefetch ----
      if (wv == 1 && l >= 32 && (t & 31) == 12) {
        const int cl = (t >> 5) + 1;
        if (cl * 32 < T) {
          const int j = l - 32;
          #pragma unroll
          for (int ii = 0; ii < 2; ++ii) {
            const int off = (2 * j + ii) * 4;
            *(f4*)&tbuf[cl & 1][off] = *(const f4*)&target[cl * 256 + off];
          }
        }
      }
      if (l == 0) adc(&cnt[0]);
    }
  } else {
    // ================= GROUP B: layer-1 + head, trails =================
    int cached0 = 0;
    const int tendB = T + 3;
    for (int t = 0; t <= tendB; ++t) {
      while (ldc(&cnt[1]) < 4 * t) {}   // own 4-wave quorum
      // ---- layer-1 cell: h1[t-1] = cell(h0[t-1], h1[t-2]) ----
      if (t >= 1 && t <= T) {
        const int need = 4 * t;         // A finished phase t-1
        while (cached0 < need) cached0 = ldc(&cnt[0]);
        const float* base = (k < 2) ? &h0r[(t - 1) & 7][32 * (k & 1)]
                                    : &h1r[(t - 2) & 7][32 * (k & 1)];
        f2 P0 = {0.f,0.f}, P1 = {0.f,0.f}, P2 = {0.f,0.f}, P3 = {0.f,0.f};
        #pragma unroll
        for (int c = 0; c < 8; ++c) {
          f4 v = *(const f4*)(base + 4 * ((c + 2 * k) & 7));
          P0 += wq[2*c] * v.lo;      P0 += wq[2*c+1] * v.hi;
          P1 += wq[16+2*c] * v.lo;   P1 += wq[16+2*c+1] * v.hi;
          P2 += wq[32+2*c] * v.lo;   P2 += wq[32+2*c+1] * v.hi;
          P3 += wq[48+2*c] * v.lo;   P3 += wq[48+2*c+1] * v.hi;
        }
        float p0 = P0.x + P0.y, p1 = P1.x + P1.y;
        float p2 = P2.x + P2.y, p3 = P3.x + P3.y;
        float g = ((p0 + qp<0x39>(p3)) + (qp<0x4E>(p2) + qp<0x93>(p1))) + b_;
        float e = __expf(-g * am);
        float s = __fdividef(1.0f, 1.0f + e);
        float a = fmaf(s, am, ab);
        float A1 = qp<0xB1>(a), A2 = qp<0x4E>(a), A3 = qp<0x1B>(a);
        if (isk0) {
          cS = A1 * cS + a * A2;
          float e2 = __expf(-2.0f * cS);
          hS = A3 * (__fdividef(2.0f, 1.0f + e2) - 1.0f);
          h1r[(t - 1) & 7][u] = hS;
        }
      }
      // ---- wv4: hid(t-3) from h1[t-3] ----
      if (wv == 4 && t >= 3 && t <= T + 2) {
        const float* hp = &h1r[(t - 3) & 7][16 * k];
        f2 pa = {0.f,0.f}, pb = {0.f,0.f};
        #pragma unroll
        for (int c = 0; c < 4; ++c) {
          f4 v = *(const f4*)(hp + 4 * ((c + k) & 3));
          pa += wh[2*c] * v.lo;     pa += wh[2*c+1] * v.hi;
          pb += wh[8+2*c] * v.lo;   pb += wh[8+2*c+1] * v.hi;
        }
        float sa = pa.x + pa.y; sa += qp<0xB1>(sa); sa += qp<0x4E>(sa);
        float sb = pb.x + pb.y; sb += qp<0xB1>(sb); sb += qp<0x4E>(sb);
        if (isk0) *(f2*)&hidS[t & 3][2 * q] = (f2){sa + bhA, sb + bhB};
      }
      // ---- wv5: out(t-4) + flush ----
      if (wv == 5) {
        if (q < 8 && t >= 4 && t <= T + 3) {
          const float* hp = &hidS[(t - 1) & 3][8 * k];
          f2 po = {0.f,0.f};
          #pragma unroll
          for (int c = 0; c < 2; ++c) {
            f4 v = *(const f4*)(hp + 4 * ((c + k) & 1));
            po += wo[2*c] * v.lo; po += wo[2*c+1] * v.hi;
          }
          float so = po.x + po.y; so += qp<0xB1>(so); so += qp<0x4E>(so);
          if (isk0) obuf[((t - 4) & 63) * NF + q] = rintf(so + bo_);
        }
        if (l >= 32 && (t & 31) == 4 && t >= 36) {
          const int j = l - 32;
          #pragma unroll
          for (int ii = 0; ii < 2; ++ii) {
            const int fidx = 2 * j + ii;
            const int s = (t - 36) + (fidx >> 1);
            const int c4 = (fidx & 1) * 4;
            *(f4*)&outp[s * NF + c4] = *(const f4*)&obuf[(s & 63) * NF + c4];
          }
        }
      }
      if (l == 0) adc(&cnt[1]);
    }
  }
  __syncthreads();

  // ================= EPILOGUE =================
  {
    const int s0 = ((T - 1) >> 5) << 5;   // last partial window
    for (int idx = tid; idx < (T - s0) * NF; idx += 512) {
      const int s = s0 + (idx >> 3);
      outp[s * NF + (idx & 7)] = obuf[(s & 63) * NF + (idx & 7)];
    }
  }
  if (isk0) {
    const int base = T * NF;
    if (!isL1) {
      outp[base + u]       = hS;   // h_final layer 0
      outp[base + 128 + u] = cS;   // c_final layer 0
    } else {
      outp[base + 64 + u]  = hS;   // h_final layer 1
      outp[base + 192 + u] = cS;   // c_final layer 1
    }
  }
}

extern "C" void kernel_launch(void* const* d_in, const int* in_sizes, int n_in,
                              void* d_out, int out_size, void* d_ws, size_t ws_size,
                              hipStream_t stream) {
  const float* h0in   = (const float*)d_in[1];
  const float* c0in   = (const float*)d_in[2];
  const float* diffp  = (const float*)d_in[3];
  const float* target = (const float*)d_in[4];
  const float* Wih0   = (const float*)d_in[5];
  const float* Whh0   = (const float*)d_in[6];
  const float* bih0   = (const float*)d_in[7];
  const float* bhh0   = (const float*)d_in[8];
  const float* Wih1   = (const float*)d_in[9];
  const float* Whh1   = (const float*)d_in[10];
  const float* bih1   = (const float*)d_in[11];
  const float* bhh1   = (const float*)d_in[12];
  const float* Whid   = (const float*)d_in[13];
  const float* bhidp  = (const float*)d_in[14];
  const float* Woutp  = (const float*)d_in[15];
  const float* boutp  = (const float*)d_in[16];
  float* outp = (float*)d_out;
  const int T = in_sizes[4] / NF;

  decoder_p10<<<dim3(1), dim3(512), 0, stream>>>(
      h0in, c0in, diffp, target,
      Wih0, Whh0, bih0, bhh0,
      Wih1, Whh1, bih1, bhh1,
      Whid, bhidp, Woutp, boutp,
      outp, T);
}